// Round 9
// baseline (297.741 us; speedup 1.0000x reference)
//
#include <hip/hip_runtime.h>

#define BQ   8
#define NQ   100
#define HWP  65536
#define TILE 128
#define KS   256        // fp32 cols staged per pass -> 1KB contiguous per row
#define NCC  32         // chunks per batch -> grid 256
#define NIT  8          // (HWP/NCC)/KS
#define LROW 256        // shorts per LDS row (KS bf16)
#define JR   13         // rows per wave (rows w+8j; 100 real rows)

typedef float  f32x4  __attribute__((ext_vector_type(4)));
typedef __bf16 bf16x8 __attribute__((ext_vector_type(8)));

__device__ __forceinline__ uint32_t pk2(float a, float b) {
    // RNE fp32 -> bf16, packed pair
    uint32_t ua = __builtin_bit_cast(uint32_t, a);
    uint32_t ub = __builtin_bit_cast(uint32_t, b);
    ua += 0x7FFFu + ((ua >> 16) & 1u);
    ub += 0x7FFFu + ((ub >> 16) & 1u);
    return (ua >> 16) | (ub & 0xFFFF0000u);
}

// One block = (batch, 2048-col chunk). 8 passes; per pass each WAVE reads
// whole 1KB row-segments (lane l -> float4 at base + l*16B): one DRAM page
// activation per 1KB (R7's win). R8's full cross-compute prefetch retained;
// R8's failure was launch_bounds(512,2) == min TWO BLOCKS/CU (HIP 2nd arg is
// blocks, not waves/EU: R2 (512,4)->cap64, R8 (512,2)->cap128 both measured)
// which capped VGPR at 128 and spilled ~230MB to scratch. (512,1) -> 1
// block/CU (the LDS reality anyway) -> 2 waves/SIMD -> 256-VGPR cap; live
// peak ~229 fits. Both operands' next-pass loads now genuinely stay in
// flight through write+barriers+compute.
__global__ __launch_bounds__(512, 1) void matcher_gemm(
    const float* __restrict__ mp, const float* __restrict__ mg,
    float* __restrict__ dotp, float* __restrict__ normA, float* __restrict__ normB)
{
    __shared__ __align__(16) unsigned short ldsA[TILE * LROW]; // 64 KiB
    __shared__ __align__(16) unsigned short ldsB[TILE * LROW]; // 64 KiB

    const int blk  = blockIdx.x;
    const int b    = blk / NCC;
    const int slot = blk - b * NCC;
    const int p0   = slot * (NIT * KS);

    const int t    = threadIdx.x;
    const int lane = t & 63;
    const int w    = t >> 6;      // wave 0..7
    const int wr   = w >> 1;      // 0..3 -> 32-row strip of C
    const int wc   = w & 1;       // 0..1 -> 64-col strip of C

    // zero the padding rows (100..127) once; never rewritten
    for (int i = t; i < (TILE - NQ) * LROW / 8; i += 512) {
        const int off = NQ * LROW + i * 8;
        *(uint4*)(ldsA + off) = uint4{0, 0, 0, 0};
        *(uint4*)(ldsB + off) = uint4{0, 0, 0, 0};
    }

    const float* Ag = mp + (size_t)b * NQ * HWP;
    const float* Bg = mg + (size_t)b * NQ * HWP;

    f32x4 acc[2][4] = {};
    float nsA[JR], nsB[JR];
    #pragma unroll
    for (int j = 0; j < JR; ++j) { nsA[j] = 0.f; nsB[j] = 0.f; }

    // LDS write offset (shorts) within a row: 16B slot = (lane>>1) ^ (w&7)
    // (owned rows all have row&7 == w&7), lane parity picks the 8B half
    const int wofs = (((lane >> 1) ^ (w & 7)) << 3) + (lane & 1) * 4;

    // staging and packed registers (static indexing throughout — rule #20)
    float4 vA[JR], vB[JR];
    uint2  pA[JR], pB[JR];

    // prologue: issue pass-0 loads
    {
        const int cb = p0 + lane * 4;
        #pragma unroll
        for (int j = 0; j < JR; ++j) {
            const int r = w + 8 * j;
            vA[j] = (r < NQ) ? *(const float4*)(Ag + (size_t)r * HWP + cb)
                             : make_float4(0.f, 0.f, 0.f, 0.f);
            vB[j] = (r < NQ) ? *(const float4*)(Bg + (size_t)r * HWP + cb)
                             : make_float4(0.f, 0.f, 0.f, 0.f);
        }
    }

    #pragma unroll 1
    for (int it = 0; it < NIT; ++it) {
        // ---- convert current pass into packed regs + accumulate norms
        //      (compiler inserts the vmcnt waits on vA/vB here)
        #pragma unroll
        for (int j = 0; j < JR; ++j) {
            nsA[j] += vA[j].x*vA[j].x + vA[j].y*vA[j].y + vA[j].z*vA[j].z + vA[j].w*vA[j].w;
            pA[j].x = pk2(vA[j].x, vA[j].y);
            pA[j].y = pk2(vA[j].z, vA[j].w);
            nsB[j] += vB[j].x*vB[j].x + vB[j].y*vB[j].y + vB[j].z*vB[j].z + vB[j].w*vB[j].w;
            pB[j].x = pk2(vB[j].x, vB[j].y);
            pB[j].y = pk2(vB[j].z, vB[j].w);
        }

        // ---- issue NEXT pass's loads now: in flight through write+compute
        if (it + 1 < NIT) {
            const int cb = p0 + (it + 1) * KS + lane * 4;
            #pragma unroll
            for (int j = 0; j < JR; ++j) {
                const int r = w + 8 * j;
                vA[j] = (r < NQ) ? *(const float4*)(Ag + (size_t)r * HWP + cb)
                                 : make_float4(0.f, 0.f, 0.f, 0.f);
                vB[j] = (r < NQ) ? *(const float4*)(Bg + (size_t)r * HWP + cb)
                                 : make_float4(0.f, 0.f, 0.f, 0.f);
            }
        }

        // ---- previous pass's ds_reads are consumed (lgkmcnt drained by
        //      their MFMA uses); barrier, then overwrite the single buffer
        __builtin_amdgcn_s_barrier();
        #pragma unroll
        for (int j = 0; j < JR; ++j) {
            const int r = w + 8 * j;
            if (r < NQ) {
                *(uint2*)(ldsA + r * LROW + wofs) = pA[j];
                *(uint2*)(ldsB + r * LROW + wofs) = pB[j];
            }
        }
        asm volatile("s_waitcnt lgkmcnt(0)" ::: "memory"); // my writes committed
        __builtin_amdgcn_s_barrier();                      // all staging visible

        // ---- compute: 8 K-steps of MFMA over the staged 256 columns
        #pragma unroll
        for (int kk = 0; kk < 8; ++kk) {
            bf16x8 af[2];
            bf16x8 bfv[4];
            #pragma unroll
            for (int m = 0; m < 2; ++m) {
                const int r  = wr * 32 + m * 16 + (lane & 15);
                const int sl = (kk * 4 + (lane >> 4)) ^ (r & 7);
                af[m] = *(const bf16x8*)(ldsA + r * LROW + sl * 8);
            }
            #pragma unroll
            for (int n = 0; n < 4; ++n) {
                const int r  = wc * 64 + n * 16 + (lane & 15);
                const int sl = (kk * 4 + (lane >> 4)) ^ (r & 7);
                bfv[n] = *(const bf16x8*)(ldsB + r * LROW + sl * 8);
            }
            #pragma unroll
            for (int m = 0; m < 2; ++m)
                #pragma unroll
                for (int n = 0; n < 4; ++n)
                    acc[m][n] = __builtin_amdgcn_mfma_f32_16x16x32_bf16(
                        af[m], bfv[n], acc[m][n], 0, 0, 0);
        }
    }

    // final per-row norm reduction: full-wave shfl tree per owned row
    #pragma unroll
    for (int j = 0; j < JR; ++j) {
        const int r = w + 8 * j;
        float sa = nsA[j], sb = nsB[j];
        #pragma unroll
        for (int m = 1; m < 64; m <<= 1) {
            sa += __shfl_xor(sa, m);
            sb += __shfl_xor(sb, m);
        }
        if (lane == 0 && r < NQ) {
            normA[(size_t)blk * TILE + r] = sa;
            normB[(size_t)blk * TILE + r] = sb;
        }
    }

    // C/D layout (HW-verified): col = lane&15, row = (lane>>4)*4 + reg
    float* dp = dotp + (size_t)blk * (TILE * TILE);
    const int ccol = lane & 15;
    const int crow = (lane >> 4) * 4;
    #pragma unroll
    for (int m = 0; m < 2; ++m) {
        #pragma unroll
        for (int n = 0; n < 4; ++n) {
            const int gr = wr * 32 + m * 16 + crow;
            const int gc = wc * 64 + n * 16 + ccol;
            #pragma unroll
            for (int j = 0; j < 4; ++j)
                dp[(size_t)(gr + j) * TILE + gc] = acc[m][n][j];
        }
    }
}

// Reduce chunk partials, apply class-agreement term and dice division.
__global__ __launch_bounds__(256) void matcher_finalize(
    const float* __restrict__ y_p, const float* __restrict__ y_gt,
    const float* __restrict__ dotp, const float* __restrict__ normA,
    const float* __restrict__ normB, float* __restrict__ out)
{
    __shared__ float sA[TILE];
    __shared__ float sB[TILE];
    const int b    = blockIdx.x >> 4;
    const int part = blockIdx.x & 15;
    const int t    = threadIdx.x;

    if (t < TILE) {
        float s = 0.f;
        for (int c = 0; c < NCC; ++c) s += normA[(size_t)(b * NCC + c) * TILE + t];
        sA[t] = s;
    } else {
        float s = 0.f;
        for (int c = 0; c < NCC; ++c) s += normB[(size_t)(b * NCC + c) * TILE + (t - TILE)];
        sB[t - TILE] = s;
    }
    __syncthreads();

    for (int i = t; i < 625; i += 256) {
        const int idx = part * 625 + i;           // 0..9999 within batch
        const int n = idx / 100;
        const int k = idx - n * 100;
        float dot = 0.f;
        for (int c = 0; c < NCC; ++c)
            dot += dotp[(size_t)(b * NCC + c) * (TILE * TILE) + n * TILE + k];
        const float yp = y_p[b * NQ + n];
        const float yg = y_gt[b * NQ + k];
        const float t1 = yp * yg + (1.f - yp) * (1.f - yg);
        out[(size_t)b * (NQ * NQ) + idx] = t1 * (2.f * dot) / (sA[n] + sB[k]);
    }
}

extern "C" void kernel_launch(void* const* d_in, const int* in_sizes, int n_in,
                              void* d_out, int out_size, void* d_ws, size_t ws_size,
                              hipStream_t stream)
{
    const float* y_p  = (const float*)d_in[0];
    const float* y_gt = (const float*)d_in[1];
    const float* m_p  = (const float*)d_in[2];
    const float* m_gt = (const float*)d_in[3];
    float* out = (float*)d_out;

    float* dotp  = (float*)d_ws;    // 17 MB at NCC=32 (fits, per R1/R4)
    float* normA = dotp + (size_t)BQ * NCC * TILE * TILE;
    float* normB = normA + (size_t)BQ * NCC * TILE;

    matcher_gemm<<<dim3(BQ * NCC), dim3(512), 0, stream>>>(
        m_p, m_gt, dotp, normA, normB);
    matcher_finalize<<<dim3(BQ * 16), dim3(256), 0, stream>>>(
        y_p, y_gt, dotp, normA, normB, out);
}

// Round 10
// 182.439 us; speedup vs baseline: 1.6320x; 1.6320x over previous
//
#include <hip/hip_runtime.h>

#define BQ   8
#define NQ   100
#define HWP  65536
#define TILE 128
#define KS   256        // fp32 cols staged per pass -> 1KB contiguous per row
#define NCC  32         // chunks per batch -> grid 256
#define NIT  8          // (HWP/NCC)/KS
#define LROW 256        // shorts per LDS row (KS bf16)
#define JR   13         // rows per wave (rows w+8j; 100 real rows)

typedef float  f32x4  __attribute__((ext_vector_type(4)));
typedef __bf16 bf16x8 __attribute__((ext_vector_type(8)));

__device__ __forceinline__ uint32_t pk2(float a, float b) {
    // RNE fp32 -> bf16, packed pair
    uint32_t ua = __builtin_bit_cast(uint32_t, a);
    uint32_t ub = __builtin_bit_cast(uint32_t, b);
    ua += 0x7FFFu + ((ua >> 16) & 1u);
    ub += 0x7FFFu + ((ub >> 16) & 1u);
    return (ua >> 16) | (ub & 0xFFFF0000u);
}

__device__ __forceinline__ float sq4(const float4& v) {
    return v.x*v.x + v.y*v.y + v.z*v.z + v.w*v.w;
}

// one ping-pong staging set: 2 rows x (A,B) = 4 float4 = 16 VGPRs
struct St { float4 a0, b0, a1, b1; };

// issue batch starting at row-index J (rows w+8J, w+8J+8)
template<int J>
__device__ __forceinline__ void issue_batch(St& s, const float* __restrict__ Ag,
                                            const float* __restrict__ Bg,
                                            int w, int cb) {
    const int r0 = w + 8 * J;
    if constexpr (J == 12) {        // rows 96..103: guard; no second row
        if (r0 < NQ) {
            s.a0 = *(const float4*)(Ag + (size_t)r0 * HWP + cb);
            s.b0 = *(const float4*)(Bg + (size_t)r0 * HWP + cb);
        } else {
            s.a0 = make_float4(0.f, 0.f, 0.f, 0.f);
            s.b0 = make_float4(0.f, 0.f, 0.f, 0.f);
        }
    } else {                        // rows <= 95: unconditional
        s.a0 = *(const float4*)(Ag + (size_t)r0 * HWP + cb);
        s.b0 = *(const float4*)(Bg + (size_t)r0 * HWP + cb);
        s.a1 = *(const float4*)(Ag + (size_t)(r0 + 8) * HWP + cb);
        s.b1 = *(const float4*)(Bg + (size_t)(r0 + 8) * HWP + cb);
    }
}

template<int J>
__device__ __forceinline__ void pack_write(const St& s,
                                           unsigned short* ldsA, unsigned short* ldsB,
                                           int w, int wofs,
                                           float (&nsA)[JR], float (&nsB)[JR]) {
    const int r0 = w + 8 * J;
    nsA[J] += sq4(s.a0);
    nsB[J] += sq4(s.b0);
    if constexpr (J == 12) {
        if (r0 < NQ) {
            uint2 ua{pk2(s.a0.x, s.a0.y), pk2(s.a0.z, s.a0.w)};
            uint2 ub{pk2(s.b0.x, s.b0.y), pk2(s.b0.z, s.b0.w)};
            *(uint2*)(ldsA + r0 * LROW + wofs) = ua;
            *(uint2*)(ldsB + r0 * LROW + wofs) = ub;
        }
    } else {
        uint2 ua0{pk2(s.a0.x, s.a0.y), pk2(s.a0.z, s.a0.w)};
        uint2 ub0{pk2(s.b0.x, s.b0.y), pk2(s.b0.z, s.b0.w)};
        *(uint2*)(ldsA + r0 * LROW + wofs) = ua0;
        *(uint2*)(ldsB + r0 * LROW + wofs) = ub0;
        nsA[J + 1] += sq4(s.a1);
        nsB[J + 1] += sq4(s.b1);
        uint2 ua1{pk2(s.a1.x, s.a1.y), pk2(s.a1.z, s.a1.w)};
        uint2 ub1{pk2(s.b1.x, s.b1.y), pk2(s.b1.z, s.b1.w)};
        *(uint2*)(ldsA + (r0 + 8) * LROW + wofs) = ua1;
        *(uint2*)(ldsB + (r0 + 8) * LROW + wofs) = ub1;
    }
}

// One block = (batch, 2048-col chunk). 8 passes of KS=256 (1KB contiguous
// per-row reads: one DRAM page activation per 1KB -- R7's win). NEW vs R7:
// row-BATCH software pipeline (4 loads / 16 regs per batch, 2 ping-pong
// sets) keeps ~2 batches continuously in flight through the pack/write
// stream, and each pass's last two issue slots prefetch the NEXT pass's
// first batches -- covering the lgkm+barrier+compute+barrier gap that was
// R7's ~30us of memory idle. Peak live regs ~125: fits the 128 ceiling the
// compiler enforces for this kernel (R8/R9: 208-reg full prefetch spilled).
__global__ __launch_bounds__(512) void matcher_gemm(
    const float* __restrict__ mp, const float* __restrict__ mg,
    float* __restrict__ dotp, float* __restrict__ normA, float* __restrict__ normB)
{
    __shared__ __align__(16) unsigned short ldsA[TILE * LROW]; // 64 KiB
    __shared__ __align__(16) unsigned short ldsB[TILE * LROW]; // 64 KiB

    const int blk  = blockIdx.x;
    const int b    = blk / NCC;
    const int slot = blk - b * NCC;
    const int p0   = slot * (NIT * KS);

    const int t    = threadIdx.x;
    const int lane = t & 63;
    const int w    = t >> 6;      // wave 0..7
    const int wr   = w >> 1;      // 0..3 -> 32-row strip of C
    const int wc   = w & 1;       // 0..1 -> 64-col strip of C

    // zero the padding rows (100..127) once; never rewritten
    for (int i = t; i < (TILE - NQ) * LROW / 8; i += 512) {
        const int off = NQ * LROW + i * 8;
        *(uint4*)(ldsA + off) = uint4{0, 0, 0, 0};
        *(uint4*)(ldsB + off) = uint4{0, 0, 0, 0};
    }

    const float* Ag = mp + (size_t)b * NQ * HWP;
    const float* Bg = mg + (size_t)b * NQ * HWP;

    f32x4 acc[2][4] = {};
    float nsA[JR], nsB[JR];
    #pragma unroll
    for (int j = 0; j < JR; ++j) { nsA[j] = 0.f; nsB[j] = 0.f; }

    // LDS write offset (shorts): 16B slot = (lane>>1) ^ (w&7), 8B half by parity
    const int wofs = (((lane >> 1) ^ (w & 7)) << 3) + (lane & 1) * 4;

    St S0, S1;

    // prologue: pass-0 batches 0,1 (global parity 0,1 -> S0,S1)
    {
        const int cb0 = p0 + lane * 4;
        issue_batch<0>(S0, Ag, Bg, w, cb0);
        issue_batch<2>(S1, Ag, Bg, w, cb0);
    }

    #pragma unroll 1
    for (int it = 0; it < NIT; ++it) {
        const int cbc  = p0 + it * KS + lane * 4;
        const int cbn  = cbc + KS;
        const bool more = (it + 1 < NIT);
        const bool odd  = (it & 1) != 0;   // batch parity flips each pass (7 odd)
        St& Sa = odd ? S1 : S0;            // set used by even b in this pass
        St& Sb = odd ? S0 : S1;

        // 7 batches: pack/write b, then issue b+2 (last two -> next pass)
        pack_write<0>(Sa, ldsA, ldsB, w, wofs, nsA, nsB);
        issue_batch<4>(Sa, Ag, Bg, w, cbc);
        pack_write<2>(Sb, ldsA, ldsB, w, wofs, nsA, nsB);
        issue_batch<6>(Sb, Ag, Bg, w, cbc);
        pack_write<4>(Sa, ldsA, ldsB, w, wofs, nsA, nsB);
        issue_batch<8>(Sa, Ag, Bg, w, cbc);
        pack_write<6>(Sb, ldsA, ldsB, w, wofs, nsA, nsB);
        issue_batch<10>(Sb, Ag, Bg, w, cbc);
        pack_write<8>(Sa, ldsA, ldsB, w, wofs, nsA, nsB);
        issue_batch<12>(Sa, Ag, Bg, w, cbc);
        pack_write<10>(Sb, ldsA, ldsB, w, wofs, nsA, nsB);
        if (more) issue_batch<0>(Sb, Ag, Bg, w, cbn);   // next-pass b0
        pack_write<12>(Sa, ldsA, ldsB, w, wofs, nsA, nsB);
        if (more) issue_batch<2>(Sa, Ag, Bg, w, cbn);   // next-pass b1

        asm volatile("s_waitcnt lgkmcnt(0)" ::: "memory"); // my writes committed
        __builtin_amdgcn_s_barrier();                      // all staging visible

        // compute: 8 K-steps of MFMA; next-pass batches 0,1 in flight under it
        #pragma unroll
        for (int kk = 0; kk < 8; ++kk) {
            bf16x8 af[2];
            bf16x8 bfv[4];
            #pragma unroll
            for (int m = 0; m < 2; ++m) {
                const int r  = wr * 32 + m * 16 + (lane & 15);
                const int sl = (kk * 4 + (lane >> 4)) ^ (r & 7);
                af[m] = *(const bf16x8*)(ldsA + r * LROW + sl * 8);
            }
            #pragma unroll
            for (int n = 0; n < 4; ++n) {
                const int r  = wc * 64 + n * 16 + (lane & 15);
                const int sl = (kk * 4 + (lane >> 4)) ^ (r & 7);
                bfv[n] = *(const bf16x8*)(ldsB + r * LROW + sl * 8);
            }
            #pragma unroll
            for (int m = 0; m < 2; ++m)
                #pragma unroll
                for (int n = 0; n < 4; ++n)
                    acc[m][n] = __builtin_amdgcn_mfma_f32_16x16x32_bf16(
                        af[m], bfv[n], acc[m][n], 0, 0, 0);
        }

        __builtin_amdgcn_s_barrier();   // reads done before next pass's writes
    }

    // final per-row norm reduction: full-wave shfl tree per owned row
    #pragma unroll
    for (int j = 0; j < JR; ++j) {
        const int r = w + 8 * j;
        float sa = nsA[j], sb = nsB[j];
        #pragma unroll
        for (int m = 1; m < 64; m <<= 1) {
            sa += __shfl_xor(sa, m);
            sb += __shfl_xor(sb, m);
        }
        if (lane == 0 && r < NQ) {
            normA[(size_t)blk * TILE + r] = sa;
            normB[(size_t)blk * TILE + r] = sb;
        }
    }

    // C/D layout (HW-verified): col = lane&15, row = (lane>>4)*4 + reg
    float* dp = dotp + (size_t)blk * (TILE * TILE);
    const int ccol = lane & 15;
    const int crow = (lane >> 4) * 4;
    #pragma unroll
    for (int m = 0; m < 2; ++m) {
        #pragma unroll
        for (int n = 0; n < 4; ++n) {
            const int gr = wr * 32 + m * 16 + crow;
            const int gc = wc * 64 + n * 16 + ccol;
            #pragma unroll
            for (int j = 0; j < 4; ++j)
                dp[(size_t)(gr + j) * TILE + gc] = acc[m][n][j];
        }
    }
}

// Reduce chunk partials, apply class-agreement term and dice division.
__global__ __launch_bounds__(256) void matcher_finalize(
    const float* __restrict__ y_p, const float* __restrict__ y_gt,
    const float* __restrict__ dotp, const float* __restrict__ normA,
    const float* __restrict__ normB, float* __restrict__ out)
{
    __shared__ float sA[TILE];
    __shared__ float sB[TILE];
    const int b    = blockIdx.x >> 4;
    const int part = blockIdx.x & 15;
    const int t    = threadIdx.x;

    if (t < TILE) {
        float s = 0.f;
        for (int c = 0; c < NCC; ++c) s += normA[(size_t)(b * NCC + c) * TILE + t];
        sA[t] = s;
    } else {
        float s = 0.f;
        for (int c = 0; c < NCC; ++c) s += normB[(size_t)(b * NCC + c) * TILE + (t - TILE)];
        sB[t - TILE] = s;
    }
    __syncthreads();

    for (int i = t; i < 625; i += 256) {
        const int idx = part * 625 + i;           // 0..9999 within batch
        const int n = idx / 100;
        const int k = idx - n * 100;
        float dot = 0.f;
        for (int c = 0; c < NCC; ++c)
            dot += dotp[(size_t)(b * NCC + c) * (TILE * TILE) + n * TILE + k];
        const float yp = y_p[b * NQ + n];
        const float yg = y_gt[b * NQ + k];
        const float t1 = yp * yg + (1.f - yp) * (1.f - yg);
        out[(size_t)b * (NQ * NQ) + idx] = t1 * (2.f * dot) / (sA[n] + sB[k]);
    }
}

extern "C" void kernel_launch(void* const* d_in, const int* in_sizes, int n_in,
                              void* d_out, int out_size, void* d_ws, size_t ws_size,
                              hipStream_t stream)
{
    const float* y_p  = (const float*)d_in[0];
    const float* y_gt = (const float*)d_in[1];
    const float* m_p  = (const float*)d_in[2];
    const float* m_gt = (const float*)d_in[3];
    float* out = (float*)d_out;

    float* dotp  = (float*)d_ws;    // 17 MB at NCC=32 (fits, per R1/R4)
    float* normA = dotp + (size_t)BQ * NCC * TILE * TILE;
    float* normB = normA + (size_t)BQ * NCC * TILE;

    matcher_gemm<<<dim3(BQ * NCC), dim3(512), 0, stream>>>(
        m_p, m_gt, dotp, normA, normB);
    matcher_finalize<<<dim3(BQ * 16), dim3(256), 0, stream>>>(
        y_p, y_gt, dotp, normA, normB, out);
}

// Round 11
// 178.916 us; speedup vs baseline: 1.6641x; 1.0197x over previous
//
#include <hip/hip_runtime.h>

#define BQ   8
#define NQ   100
#define HWP  65536
#define TILE 128
#define KS   256        // fp32 cols staged per pass -> 1KB contiguous per row
#define NCC  32         // chunks per batch -> grid 256
#define NIT  8          // (HWP/NCC)/KS
#define LROW 256        // shorts per LDS row (KS bf16)
#define JR   13         // rows per wave (rows w+8j; 100 real rows)

typedef float  f32x4  __attribute__((ext_vector_type(4)));
typedef __bf16 bf16x8 __attribute__((ext_vector_type(8)));

__device__ __forceinline__ uint32_t pk2(float a, float b) {
    // RNE fp32 -> bf16, packed pair
    uint32_t ua = __builtin_bit_cast(uint32_t, a);
    uint32_t ub = __builtin_bit_cast(uint32_t, b);
    ua += 0x7FFFu + ((ua >> 16) & 1u);
    ub += 0x7FFFu + ((ub >> 16) & 1u);
    return (ua >> 16) | (ub & 0xFFFF0000u);
}

__device__ __forceinline__ float sq4(const float4& v) {
    return v.x*v.x + v.y*v.y + v.z*v.z + v.w*v.w;
}

// one ping-pong staging set: 2 rows x (A,B) = 4 float4 = 16 VGPRs
struct St { float4 a0, b0, a1, b1; };

// issue batch starting at row-index J (rows w+8J, w+8J+8)
template<int J>
__device__ __forceinline__ void issue_batch(St& s, const float* __restrict__ Ag,
                                            const float* __restrict__ Bg,
                                            int w, int cb) {
    const int r0 = w + 8 * J;
    if constexpr (J == 12) {        // rows 96..103: guard; no second row
        if (r0 < NQ) {
            s.a0 = *(const float4*)(Ag + (size_t)r0 * HWP + cb);
            s.b0 = *(const float4*)(Bg + (size_t)r0 * HWP + cb);
        } else {
            s.a0 = make_float4(0.f, 0.f, 0.f, 0.f);
            s.b0 = make_float4(0.f, 0.f, 0.f, 0.f);
        }
    } else {                        // rows <= 95: unconditional
        s.a0 = *(const float4*)(Ag + (size_t)r0 * HWP + cb);
        s.b0 = *(const float4*)(Bg + (size_t)r0 * HWP + cb);
        s.a1 = *(const float4*)(Ag + (size_t)(r0 + 8) * HWP + cb);
        s.b1 = *(const float4*)(Bg + (size_t)(r0 + 8) * HWP + cb);
    }
}

template<int J>
__device__ __forceinline__ void pack_write(const St& s,
                                           unsigned short* ldsA, unsigned short* ldsB,
                                           int w, int wofs,
                                           float (&nsA)[JR], float (&nsB)[JR]) {
    const int r0 = w + 8 * J;
    nsA[J] += sq4(s.a0);
    nsB[J] += sq4(s.b0);
    if constexpr (J == 12) {
        if (r0 < NQ) {
            uint2 ua{pk2(s.a0.x, s.a0.y), pk2(s.a0.z, s.a0.w)};
            uint2 ub{pk2(s.b0.x, s.b0.y), pk2(s.b0.z, s.b0.w)};
            *(uint2*)(ldsA + r0 * LROW + wofs) = ua;
            *(uint2*)(ldsB + r0 * LROW + wofs) = ub;
        }
    } else {
        uint2 ua0{pk2(s.a0.x, s.a0.y), pk2(s.a0.z, s.a0.w)};
        uint2 ub0{pk2(s.b0.x, s.b0.y), pk2(s.b0.z, s.b0.w)};
        *(uint2*)(ldsA + r0 * LROW + wofs) = ua0;
        *(uint2*)(ldsB + r0 * LROW + wofs) = ub0;
        nsA[J + 1] += sq4(s.a1);
        nsB[J + 1] += sq4(s.b1);
        uint2 ua1{pk2(s.a1.x, s.a1.y), pk2(s.a1.z, s.a1.w)};
        uint2 ub1{pk2(s.b1.x, s.b1.y), pk2(s.b1.z, s.b1.w)};
        *(uint2*)(ldsA + (r0 + 8) * LROW + wofs) = ua1;
        *(uint2*)(ldsB + (r0 + 8) * LROW + wofs) = ub1;
    }
}

// One full pass: 7 pack/issue slots (last two issues prefetch NEXT pass's
// first batches), lgkm+barrier, 8 MFMA K-steps, barrier. Sa/Sb are bound
// STATICALLY at each call site (R10's runtime `odd ? S1 : S0` reference
// select forced S0/S1 into scratch -- the 250MB spill).
__device__ __forceinline__ void do_pass(
    St& Sa, St& Sb, int it, bool more,
    const float* __restrict__ Ag, const float* __restrict__ Bg,
    unsigned short* ldsA, unsigned short* ldsB,
    int w, int wofs, int lane, int wr, int wc, int p0,
    float (&nsA)[JR], float (&nsB)[JR], f32x4 (&acc)[2][4])
{
    const int cbc = p0 + it * KS + lane * 4;
    const int cbn = cbc + KS;

    pack_write<0>(Sa, ldsA, ldsB, w, wofs, nsA, nsB);
    issue_batch<4>(Sa, Ag, Bg, w, cbc);
    pack_write<2>(Sb, ldsA, ldsB, w, wofs, nsA, nsB);
    issue_batch<6>(Sb, Ag, Bg, w, cbc);
    pack_write<4>(Sa, ldsA, ldsB, w, wofs, nsA, nsB);
    issue_batch<8>(Sa, Ag, Bg, w, cbc);
    pack_write<6>(Sb, ldsA, ldsB, w, wofs, nsA, nsB);
    issue_batch<10>(Sb, Ag, Bg, w, cbc);
    pack_write<8>(Sa, ldsA, ldsB, w, wofs, nsA, nsB);
    issue_batch<12>(Sa, Ag, Bg, w, cbc);
    pack_write<10>(Sb, ldsA, ldsB, w, wofs, nsA, nsB);
    if (more) issue_batch<0>(Sb, Ag, Bg, w, cbn);   // next-pass batch 0
    pack_write<12>(Sa, ldsA, ldsB, w, wofs, nsA, nsB);
    if (more) issue_batch<2>(Sa, Ag, Bg, w, cbn);   // next-pass batch 1

    asm volatile("s_waitcnt lgkmcnt(0)" ::: "memory"); // my ds_writes committed
    __builtin_amdgcn_s_barrier();                      // all staging visible

    #pragma unroll
    for (int kk = 0; kk < 8; ++kk) {
        bf16x8 af[2];
        bf16x8 bfv[4];
        #pragma unroll
        for (int m = 0; m < 2; ++m) {
            const int r  = wr * 32 + m * 16 + (lane & 15);
            const int sl = (kk * 4 + (lane >> 4)) ^ (r & 7);
            af[m] = *(const bf16x8*)(ldsA + r * LROW + sl * 8);
        }
        #pragma unroll
        for (int n = 0; n < 4; ++n) {
            const int r  = wc * 64 + n * 16 + (lane & 15);
            const int sl = (kk * 4 + (lane >> 4)) ^ (r & 7);
            bfv[n] = *(const bf16x8*)(ldsB + r * LROW + sl * 8);
        }
        #pragma unroll
        for (int m = 0; m < 2; ++m)
            #pragma unroll
            for (int n = 0; n < 4; ++n)
                acc[m][n] = __builtin_amdgcn_mfma_f32_16x16x32_bf16(
                    af[m], bfv[n], acc[m][n], 0, 0, 0);
    }

    __builtin_amdgcn_s_barrier();   // reads done before next pass's writes
}

// One block = (batch, 2048-col chunk). 8 passes of KS=256 (1KB contiguous
// per-row reads -> one DRAM page activation per 1KB: R7's win). Row-batch
// software pipeline (16-reg batches, ping-pong S0/S1) keeps ~2 batches
// continuously in flight through the pack/write stream and across the
// barrier+compute gap. Parity handled by compile-time call-site binding.
__global__ __launch_bounds__(512) void matcher_gemm(
    const float* __restrict__ mp, const float* __restrict__ mg,
    float* __restrict__ dotp, float* __restrict__ normA, float* __restrict__ normB)
{
    __shared__ __align__(16) unsigned short ldsA[TILE * LROW]; // 64 KiB
    __shared__ __align__(16) unsigned short ldsB[TILE * LROW]; // 64 KiB

    const int blk  = blockIdx.x;
    const int b    = blk / NCC;
    const int slot = blk - b * NCC;
    const int p0   = slot * (NIT * KS);

    const int t    = threadIdx.x;
    const int lane = t & 63;
    const int w    = t >> 6;      // wave 0..7
    const int wr   = w >> 1;      // 0..3 -> 32-row strip of C
    const int wc   = w & 1;       // 0..1 -> 64-col strip of C

    // zero the padding rows (100..127) once; never rewritten
    for (int i = t; i < (TILE - NQ) * LROW / 8; i += 512) {
        const int off = NQ * LROW + i * 8;
        *(uint4*)(ldsA + off) = uint4{0, 0, 0, 0};
        *(uint4*)(ldsB + off) = uint4{0, 0, 0, 0};
    }

    const float* Ag = mp + (size_t)b * NQ * HWP;
    const float* Bg = mg + (size_t)b * NQ * HWP;

    f32x4 acc[2][4] = {};
    float nsA[JR], nsB[JR];
    #pragma unroll
    for (int j = 0; j < JR; ++j) { nsA[j] = 0.f; nsB[j] = 0.f; }

    // LDS write offset (shorts): 16B slot = (lane>>1) ^ (w&7), 8B half by parity
    const int wofs = (((lane >> 1) ^ (w & 7)) << 3) + (lane & 1) * 4;

    St S0, S1;

    // prologue: pass-0 batches 0,1 -> S0,S1
    {
        const int cb0 = p0 + lane * 4;
        issue_batch<0>(S0, Ag, Bg, w, cb0);
        issue_batch<2>(S1, Ag, Bg, w, cb0);
    }

    #pragma unroll 1
    for (int it = 0; it < NIT; it += 2) {
        // even pass: batches 0,2,4,.. live in S0; 2,6,10 in S1 (Sa=S0)
        do_pass(S0, S1, it,     true,
                Ag, Bg, ldsA, ldsB, w, wofs, lane, wr, wc, p0, nsA, nsB, acc);
        // odd pass: prefetched batch0 landed in S1, batch1 in S0 (Sa=S1)
        do_pass(S1, S0, it + 1, (it + 2) < NIT,
                Ag, Bg, ldsA, ldsB, w, wofs, lane, wr, wc, p0, nsA, nsB, acc);
    }

    // final per-row norm reduction: full-wave shfl tree per owned row
    #pragma unroll
    for (int j = 0; j < JR; ++j) {
        const int r = w + 8 * j;
        float sa = nsA[j], sb = nsB[j];
        #pragma unroll
        for (int m = 1; m < 64; m <<= 1) {
            sa += __shfl_xor(sa, m);
            sb += __shfl_xor(sb, m);
        }
        if (lane == 0 && r < NQ) {
            normA[(size_t)blk * TILE + r] = sa;
            normB[(size_t)blk * TILE + r] = sb;
        }
    }

    // C/D layout (HW-verified): col = lane&15, row = (lane>>4)*4 + reg
    float* dp = dotp + (size_t)blk * (TILE * TILE);
    const int ccol = lane & 15;
    const int crow = (lane >> 4) * 4;
    #pragma unroll
    for (int m = 0; m < 2; ++m) {
        #pragma unroll
        for (int n = 0; n < 4; ++n) {
            const int gr = wr * 32 + m * 16 + crow;
            const int gc = wc * 64 + n * 16 + ccol;
            #pragma unroll
            for (int j = 0; j < 4; ++j)
                dp[(size_t)(gr + j) * TILE + gc] = acc[m][n][j];
        }
    }
}

// Reduce chunk partials, apply class-agreement term and dice division.
__global__ __launch_bounds__(256) void matcher_finalize(
    const float* __restrict__ y_p, const float* __restrict__ y_gt,
    const float* __restrict__ dotp, const float* __restrict__ normA,
    const float* __restrict__ normB, float* __restrict__ out)
{
    __shared__ float sA[TILE];
    __shared__ float sB[TILE];
    const int b    = blockIdx.x >> 4;
    const int part = blockIdx.x & 15;
    const int t    = threadIdx.x;

    if (t < TILE) {
        float s = 0.f;
        for (int c = 0; c < NCC; ++c) s += normA[(size_t)(b * NCC + c) * TILE + t];
        sA[t] = s;
    } else {
        float s = 0.f;
        for (int c = 0; c < NCC; ++c) s += normB[(size_t)(b * NCC + c) * TILE + (t - TILE)];
        sB[t - TILE] = s;
    }
    __syncthreads();

    for (int i = t; i < 625; i += 256) {
        const int idx = part * 625 + i;           // 0..9999 within batch
        const int n = idx / 100;
        const int k = idx - n * 100;
        float dot = 0.f;
        for (int c = 0; c < NCC; ++c)
            dot += dotp[(size_t)(b * NCC + c) * (TILE * TILE) + n * TILE + k];
        const float yp = y_p[b * NQ + n];
        const float yg = y_gt[b * NQ + k];
        const float t1 = yp * yg + (1.f - yp) * (1.f - yg);
        out[(size_t)b * (NQ * NQ) + idx] = t1 * (2.f * dot) / (sA[n] + sB[k]);
    }
}

extern "C" void kernel_launch(void* const* d_in, const int* in_sizes, int n_in,
                              void* d_out, int out_size, void* d_ws, size_t ws_size,
                              hipStream_t stream)
{
    const float* y_p  = (const float*)d_in[0];
    const float* y_gt = (const float*)d_in[1];
    const float* m_p  = (const float*)d_in[2];
    const float* m_gt = (const float*)d_in[3];
    float* out = (float*)d_out;

    float* dotp  = (float*)d_ws;    // 17 MB at NCC=32 (fits, per R1/R4)
    float* normA = dotp + (size_t)BQ * NCC * TILE * TILE;
    float* normB = normA + (size_t)BQ * NCC * TILE;

    matcher_gemm<<<dim3(BQ * NCC), dim3(512), 0, stream>>>(
        m_p, m_gt, dotp, normA, normB);
    matcher_finalize<<<dim3(BQ * 16), dim3(256), 0, stream>>>(
        y_p, y_gt, dotp, normA, normB, out);
}

// Round 12
// 90.483 us; speedup vs baseline: 3.2906x; 1.9773x over previous
//
#include <hip/hip_runtime.h>

#define BQ   8
#define NQ   100
#define HWP  65536
#define TILE 128
#define KS   256        // fp32 cols staged per pass -> 1KB contiguous per row
#define NCC  32         // chunks per batch -> grid 256
#define NIT  8          // (HWP/NCC)/KS
#define LROW 256        // shorts per LDS row (KS bf16)

typedef float  f32x4  __attribute__((ext_vector_type(4)));
typedef __bf16 bf16x8 __attribute__((ext_vector_type(8)));

__device__ __forceinline__ uint32_t pk2(float a, float b) {
    // RNE fp32 -> bf16, packed pair
    uint32_t ua = __builtin_bit_cast(uint32_t, a);
    uint32_t ub = __builtin_bit_cast(uint32_t, b);
    ua += 0x7FFFu + ((ua >> 16) & 1u);
    ub += 0x7FFFu + ((ub >> 16) & 1u);
    return (ua >> 16) | (ub & 0xFFFF0000u);
}

// one ping-pong staging set: 2 rows x (A,B) = 4 float4 = 16 VGPRs
struct St { float4 a0, b0, a1, b1; };

// issue batch starting at row-index J (rows w+8J, w+8J+8)
template<int J>
__device__ __forceinline__ void issue_batch(St& s, const float* __restrict__ Ag,
                                            const float* __restrict__ Bg,
                                            int w, int cb) {
    const int r0 = w + 8 * J;
    if constexpr (J == 12) {        // rows 96..103: guard; no second row
        if (r0 < NQ) {
            s.a0 = *(const float4*)(Ag + (size_t)r0 * HWP + cb);
            s.b0 = *(const float4*)(Bg + (size_t)r0 * HWP + cb);
        } else {
            s.a0 = make_float4(0.f, 0.f, 0.f, 0.f);
            s.b0 = make_float4(0.f, 0.f, 0.f, 0.f);
        }
    } else {                        // rows <= 95: unconditional
        s.a0 = *(const float4*)(Ag + (size_t)r0 * HWP + cb);
        s.b0 = *(const float4*)(Bg + (size_t)r0 * HWP + cb);
        s.a1 = *(const float4*)(Ag + (size_t)(r0 + 8) * HWP + cb);
        s.b1 = *(const float4*)(Bg + (size_t)(r0 + 8) * HWP + cb);
    }
}

// pack to bf16 and write swizzled LDS (no norm math here anymore: the norm
// accumulators' 26 always-live VGPRs were what pushed R11 over the 128
// ceiling; norms now come from the MFMA fragments in the compute phase)
template<int J>
__device__ __forceinline__ void pack_write(const St& s,
                                           unsigned short* ldsA, unsigned short* ldsB,
                                           int w, int wofs) {
    const int r0 = w + 8 * J;
    if constexpr (J == 12) {
        if (r0 < NQ) {
            uint2 ua{pk2(s.a0.x, s.a0.y), pk2(s.a0.z, s.a0.w)};
            uint2 ub{pk2(s.b0.x, s.b0.y), pk2(s.b0.z, s.b0.w)};
            *(uint2*)(ldsA + r0 * LROW + wofs) = ua;
            *(uint2*)(ldsB + r0 * LROW + wofs) = ub;
        }
    } else {
        uint2 ua0{pk2(s.a0.x, s.a0.y), pk2(s.a0.z, s.a0.w)};
        uint2 ub0{pk2(s.b0.x, s.b0.y), pk2(s.b0.z, s.b0.w)};
        *(uint2*)(ldsA + r0 * LROW + wofs) = ua0;
        *(uint2*)(ldsB + r0 * LROW + wofs) = ub0;
        uint2 ua1{pk2(s.a1.x, s.a1.y), pk2(s.a1.z, s.a1.w)};
        uint2 ub1{pk2(s.b1.x, s.b1.y), pk2(s.b1.z, s.b1.w)};
        *(uint2*)(ldsA + (r0 + 8) * LROW + wofs) = ua1;
        *(uint2*)(ldsB + (r0 + 8) * LROW + wofs) = ub1;
    }
}

// One full pass: 7 pack/issue slots (last two issues prefetch NEXT pass's
// first batches), lgkm+barrier, 8 MFMA K-steps with fragment-sourced norm
// accumulation, barrier. Sa/Sb bound statically at each call site.
__device__ __forceinline__ void do_pass(
    St& Sa, St& Sb, int it, bool more,
    const float* __restrict__ Ag, const float* __restrict__ Bg,
    unsigned short* ldsA, unsigned short* ldsB,
    int w, int wofs, int lane, int wr, int wc, int p0,
    float (&nsa)[2], float& nsb, f32x4 (&acc)[2][4])
{
    const int cbc = p0 + it * KS + lane * 4;
    const int cbn = cbc + KS;

    pack_write<0>(Sa, ldsA, ldsB, w, wofs);
    issue_batch<4>(Sa, Ag, Bg, w, cbc);
    pack_write<2>(Sb, ldsA, ldsB, w, wofs);
    issue_batch<6>(Sb, Ag, Bg, w, cbc);
    pack_write<4>(Sa, ldsA, ldsB, w, wofs);
    issue_batch<8>(Sa, Ag, Bg, w, cbc);
    pack_write<6>(Sb, ldsA, ldsB, w, wofs);
    issue_batch<10>(Sb, Ag, Bg, w, cbc);
    pack_write<8>(Sa, ldsA, ldsB, w, wofs);
    issue_batch<12>(Sa, Ag, Bg, w, cbc);
    pack_write<10>(Sb, ldsA, ldsB, w, wofs);
    if (more) issue_batch<0>(Sb, Ag, Bg, w, cbn);   // next-pass batch 0
    pack_write<12>(Sa, ldsA, ldsB, w, wofs);
    if (more) issue_batch<2>(Sa, Ag, Bg, w, cbn);   // next-pass batch 1

    asm volatile("s_waitcnt lgkmcnt(0)" ::: "memory"); // my ds_writes committed
    __builtin_amdgcn_s_barrier();                      // all staging visible

    #pragma unroll
    for (int kk = 0; kk < 8; ++kk) {
        bf16x8 af[2];
        bf16x8 bfv[4];
        #pragma unroll
        for (int m = 0; m < 2; ++m) {
            const int r  = wr * 32 + m * 16 + (lane & 15);
            const int sl = (kk * 4 + (lane >> 4)) ^ (r & 7);
            af[m] = *(const bf16x8*)(ldsA + r * LROW + sl * 8);
        }
        #pragma unroll
        for (int n = 0; n < 4; ++n) {
            const int r  = wc * 64 + n * 16 + (lane & 15);
            const int sl = (kk * 4 + (lane >> 4)) ^ (r & 7);
            bfv[n] = *(const bf16x8*)(ldsB + r * LROW + sl * 8);
        }

        // norm accumulation from fragments (each (row, k-chunk) read once
        // per wc for A / once per wr for B -> dedupe by wave role).
        // bf16-sourced norms: ~1e-6 relative bias, invisible vs threshold.
        if (wc == 0) {
            #pragma unroll
            for (int m = 0; m < 2; ++m)
                #pragma unroll
                for (int i = 0; i < 8; ++i) {
                    const float x = (float)af[m][i];
                    nsa[m] = fmaf(x, x, nsa[m]);
                }
        }
        #pragma unroll
        for (int n = 0; n < 4; ++n)
            if (n == wr) {  // compile-time n, wave-uniform check: no dyn index
                #pragma unroll
                for (int i = 0; i < 8; ++i) {
                    const float x = (float)bfv[n][i];
                    nsb = fmaf(x, x, nsb);
                }
            }

        #pragma unroll
        for (int m = 0; m < 2; ++m)
            #pragma unroll
            for (int n = 0; n < 4; ++n)
                acc[m][n] = __builtin_amdgcn_mfma_f32_16x16x32_bf16(
                    af[m], bfv[n], acc[m][n], 0, 0, 0);
    }

    __builtin_amdgcn_s_barrier();   // reads done before next pass's writes
}

// One block = (batch, 2048-col chunk). 8 passes of KS=256 (1KB contiguous
// per-row reads -> one DRAM page activation per 1KB: R7's win). Row-batch
// software pipeline (16-reg batches, ping-pong S0/S1) keeps ~2 batches
// continuously in flight through the pack/write stream and across the
// barrier+compute gap. Live-reg peak ~105 after moving norms to fragments.
__global__ __launch_bounds__(512) void matcher_gemm(
    const float* __restrict__ mp, const float* __restrict__ mg,
    float* __restrict__ dotp, float* __restrict__ normA, float* __restrict__ normB)
{
    __shared__ __align__(16) unsigned short ldsA[TILE * LROW]; // 64 KiB
    __shared__ __align__(16) unsigned short ldsB[TILE * LROW]; // 64 KiB

    const int blk  = blockIdx.x;
    const int b    = blk / NCC;
    const int slot = blk - b * NCC;
    const int p0   = slot * (NIT * KS);

    const int t    = threadIdx.x;
    const int lane = t & 63;
    const int w    = t >> 6;      // wave 0..7
    const int wr   = w >> 1;      // 0..3 -> 32-row strip of C
    const int wc   = w & 1;       // 0..1 -> 64-col strip of C

    // zero the padding rows (100..127) once; never rewritten
    for (int i = t; i < (TILE - NQ) * LROW / 8; i += 512) {
        const int off = NQ * LROW + i * 8;
        *(uint4*)(ldsA + off) = uint4{0, 0, 0, 0};
        *(uint4*)(ldsB + off) = uint4{0, 0, 0, 0};
    }

    const float* Ag = mp + (size_t)b * NQ * HWP;
    const float* Bg = mg + (size_t)b * NQ * HWP;

    f32x4 acc[2][4] = {};
    float nsa[2] = {0.f, 0.f};
    float nsb = 0.f;

    // LDS write offset (shorts): 16B slot = (lane>>1) ^ (w&7), 8B half by parity
    const int wofs = (((lane >> 1) ^ (w & 7)) << 3) + (lane & 1) * 4;

    St S0, S1;

    // prologue: pass-0 batches 0,1 -> S0,S1
    {
        const int cb0 = p0 + lane * 4;
        issue_batch<0>(S0, Ag, Bg, w, cb0);
        issue_batch<2>(S1, Ag, Bg, w, cb0);
    }

    #pragma unroll 1
    for (int it = 0; it < NIT; it += 2) {
        // even pass: Sa=S0; odd pass: prefetched b0 landed in S1 -> Sa=S1
        do_pass(S0, S1, it,     true,
                Ag, Bg, ldsA, ldsB, w, wofs, lane, wr, wc, p0, nsa, nsb, acc);
        do_pass(S1, S0, it + 1, (it + 2) < NIT,
                Ag, Bg, ldsA, ldsB, w, wofs, lane, wr, wc, p0, nsa, nsb, acc);
    }

    // ---- norm epilogue ----
    // B norms: every wave owns fragment n==wr -> rows wc*64 + wr*16 + 0..15
    {
        float s = nsb;
        s += __shfl_xor(s, 16);
        s += __shfl_xor(s, 32);
        if (lane < 16)
            normB[(size_t)blk * TILE + wc * 64 + wr * 16 + lane] = s;
    }
    // A norms: wc==0 waves own rows wr*32 + m*16 + 0..15
    if (wc == 0) {
        #pragma unroll
        for (int m = 0; m < 2; ++m) {
            float s = nsa[m];
            s += __shfl_xor(s, 16);
            s += __shfl_xor(s, 32);
            if (lane < 16)
                normA[(size_t)blk * TILE + wr * 32 + m * 16 + lane] = s;
        }
    }

    // C/D layout (HW-verified): col = lane&15, row = (lane>>4)*4 + reg
    float* dp = dotp + (size_t)blk * (TILE * TILE);
    const int ccol = lane & 15;
    const int crow = (lane >> 4) * 4;
    #pragma unroll
    for (int m = 0; m < 2; ++m) {
        #pragma unroll
        for (int n = 0; n < 4; ++n) {
            const int gr = wr * 32 + m * 16 + crow;
            const int gc = wc * 64 + n * 16 + ccol;
            #pragma unroll
            for (int j = 0; j < 4; ++j)
                dp[(size_t)(gr + j) * TILE + gc] = acc[m][n][j];
        }
    }
}

// Reduce chunk partials, apply class-agreement term and dice division.
__global__ __launch_bounds__(256) void matcher_finalize(
    const float* __restrict__ y_p, const float* __restrict__ y_gt,
    const float* __restrict__ dotp, const float* __restrict__ normA,
    const float* __restrict__ normB, float* __restrict__ out)
{
    __shared__ float sA[TILE];
    __shared__ float sB[TILE];
    const int b    = blockIdx.x >> 4;
    const int part = blockIdx.x & 15;
    const int t    = threadIdx.x;

    if (t < TILE) {
        float s = 0.f;
        for (int c = 0; c < NCC; ++c) s += normA[(size_t)(b * NCC + c) * TILE + t];
        sA[t] = s;
    } else {
        float s = 0.f;
        for (int c = 0; c < NCC; ++c) s += normB[(size_t)(b * NCC + c) * TILE + (t - TILE)];
        sB[t - TILE] = s;
    }
    __syncthreads();

    for (int i = t; i < 625; i += 256) {
        const int idx = part * 625 + i;           // 0..9999 within batch
        const int n = idx / 100;
        const int k = idx - n * 100;
        float dot = 0.f;
        for (int c = 0; c < NCC; ++c)
            dot += dotp[(size_t)(b * NCC + c) * (TILE * TILE) + n * TILE + k];
        const float yp = y_p[b * NQ + n];
        const float yg = y_gt[b * NQ + k];
        const float t1 = yp * yg + (1.f - yp) * (1.f - yg);
        out[(size_t)b * (NQ * NQ) + idx] = t1 * (2.f * dot) / (sA[n] + sB[k]);
    }
}

extern "C" void kernel_launch(void* const* d_in, const int* in_sizes, int n_in,
                              void* d_out, int out_size, void* d_ws, size_t ws_size,
                              hipStream_t stream)
{
    const float* y_p  = (const float*)d_in[0];
    const float* y_gt = (const float*)d_in[1];
    const float* m_p  = (const float*)d_in[2];
    const float* m_gt = (const float*)d_in[3];
    float* out = (float*)d_out;

    float* dotp  = (float*)d_ws;    // 17 MB at NCC=32 (fits, per R1/R4)
    float* normA = dotp + (size_t)BQ * NCC * TILE * TILE;
    float* normB = normA + (size_t)BQ * NCC * TILE;

    matcher_gemm<<<dim3(BQ * NCC), dim3(512), 0, stream>>>(
        m_p, m_gt, dotp, normA, normB);
    matcher_finalize<<<dim3(BQ * 16), dim3(256), 0, stream>>>(
        y_p, y_gt, dotp, normA, normB, out);
}